// Round 1
// baseline (3521.066 us; speedup 1.0000x reference)
//
#include <hip/hip_runtime.h>

// ---------------- problem constants ----------------
#define NUSER 200000
#define NPROD 100000
#define NCAT    2000
#define NQRY   50000
#define EBUYS  500000
#define ESEARCH 300000
#define EMATCH  300000
#define EIN     100000
#define HID 128

// type ids: 0=user 1=product 2=category 3=query
// relations t=0..7 (weight index):
//  t0 user->product (buys), t1 product->user (rev_buys)
//  t2 user->query (searches), t3 query->user (rev_searches)
//  t4 query->product (matches), t5 product->query (rev_matches)
//  t6 product->category (in), t7 category->product (rev_in)

// ---------------- CSR build ----------------
__global__ __launch_bounds__(256) void count_kernel(const int* __restrict__ dst, int E,
                                                    int* __restrict__ cnt) {
    int i = blockIdx.x * 256 + threadIdx.x;
    if (i < E) atomicAdd(&cnt[dst[i]], 1);
}

// 4096 elements per block partial sums
__global__ __launch_bounds__(256) void scan_partial(const int* __restrict__ cnt, int n,
                                                    int* __restrict__ bsums) {
    __shared__ int sd[256];
    int base = blockIdx.x * 4096;
    int s = 0;
    for (int j = threadIdx.x; j < 4096; j += 256) {
        int idx = base + j;
        s += (idx < n) ? cnt[idx] : 0;
    }
    sd[threadIdx.x] = s;
    __syncthreads();
    for (int st = 128; st > 0; st >>= 1) {
        if (threadIdx.x < st) sd[threadIdx.x] += sd[threadIdx.x + st];
        __syncthreads();
    }
    if (threadIdx.x == 0) bsums[blockIdx.x] = sd[0];
}

// exclusive scan of block sums (nb <= 64), one wave
__global__ __launch_bounds__(64) void scan_bsums(int* __restrict__ bs, int nb) {
    int lane = threadIdx.x;
    int orig = (lane < nb) ? bs[lane] : 0;
    int v = orig;
    for (int off = 1; off < 64; off <<= 1) {
        int t = __shfl_up(v, off);
        if (lane >= off) v += t;
    }
    if (lane < nb) bs[lane] = v - orig;  // exclusive
}

__global__ __launch_bounds__(256) void scan_final(const int* __restrict__ cnt, int n,
                                                  const int* __restrict__ bsums,
                                                  int* __restrict__ offs) {
    __shared__ int tsum[256];
    int base = blockIdx.x * 4096;
    int tid = threadIdx.x;
    int local[16];
    int s = 0;
#pragma unroll
    for (int j = 0; j < 16; ++j) {
        int idx = base + tid * 16 + j;
        int v = (idx < n) ? cnt[idx] : 0;
        s += v;
        local[j] = s;  // inclusive within thread
    }
    tsum[tid] = s;
    __syncthreads();
    int v = s;
    for (int off = 1; off < 256; off <<= 1) {
        int t = (tid >= off) ? tsum[tid - off] : 0;
        __syncthreads();
        v += t;
        tsum[tid] = v;
        __syncthreads();
    }
    int tpre = v - s;  // exclusive across threads
    int bpre = bsums[blockIdx.x];
#pragma unroll
    for (int j = 0; j < 16; ++j) {
        int idx = base + tid * 16 + j;
        if (idx < n) offs[idx + 1] = bpre + tpre + local[j];
    }
    if (blockIdx.x == 0 && tid == 0) offs[0] = 0;
}

__global__ __launch_bounds__(256) void fill_kernel(const int* __restrict__ src,
                                                   const int* __restrict__ dst,
                                                   const float* __restrict__ w, int E,
                                                   const int* __restrict__ offs,
                                                   int* __restrict__ fill,
                                                   int* __restrict__ csr_src,
                                                   float* __restrict__ csr_w) {
    int i = blockIdx.x * 256 + threadIdx.x;
    if (i >= E) return;
    int d = dst[i];
    int slot = offs[d] + atomicAdd(&fill[d], 1);
    csr_src[slot] = src[i];
    csr_w[slot] = w[i];
}

// ---------------- Wl pre-sum per dst type ----------------
// block b = layer*4 + dsttype
__global__ __launch_bounds__(256) void wlsum_kernel(const float* __restrict__ W1_l,
                                                    const float* __restrict__ b1,
                                                    const float* __restrict__ W2_l,
                                                    const float* __restrict__ b2,
                                                    float* __restrict__ Wlsum,
                                                    float* __restrict__ bsum) {
    int layer = blockIdx.x >> 2, d = blockIdx.x & 3;
    const float* W = layer ? W2_l : W1_l;
    const float* b = layer ? b2 : b1;
    int rels[3];
    int nr;
    if (d == 0) { rels[0] = 1; rels[1] = 3; nr = 2; }            // user
    else if (d == 1) { rels[0] = 0; rels[1] = 4; rels[2] = 7; nr = 3; }  // product
    else if (d == 2) { rels[0] = 6; nr = 1; }                    // category
    else { rels[0] = 2; rels[1] = 5; nr = 2; }                   // query
    float* Wo = Wlsum + (size_t)blockIdx.x * 16384;
    float* bo = bsum + (size_t)blockIdx.x * 128;
    for (int i = threadIdx.x; i < 16384; i += 256) {
        float s = 0.f;
        for (int r = 0; r < nr; ++r) s += W[rels[r] * 16384 + i];
        Wo[i] = s;
    }
    if (threadIdx.x < 128) {
        float s = 0.f;
        for (int r = 0; r < nr; ++r) s += b[rels[r] * 128 + threadIdx.x];
        bo[threadIdx.x] = s;
    }
}

// ---------------- CSR gather-reduce (scatter-mean) ----------------
// one wave per dst row; 64 lanes x float2 = 128 feats
__global__ __launch_bounds__(256) void agg_kernel(const float* __restrict__ X,
                                                  const int* __restrict__ offs,
                                                  const int* __restrict__ csr_src,
                                                  const float* __restrict__ csr_w,
                                                  float* __restrict__ agg, int n_dst) {
    int row = blockIdx.x * 4 + (threadIdx.x >> 6);
    if (row >= n_dst) return;
    int lane = threadIdx.x & 63;
    int b = offs[row], e = offs[row + 1];
    float ax = 0.f, ay = 0.f;
    for (int i = b; i < e; ++i) {
        int s = csr_src[i];
        float w = csr_w[i];
        float2 v = *(const float2*)(X + (size_t)s * 128 + lane * 2);
        ax += w * v.x;
        ay += w * v.y;
    }
    int deg = e - b;
    float inv = deg > 0 ? 1.f / (float)deg : 0.f;
    float2 o = {ax * inv, ay * inv};
    *(float2*)(agg + (size_t)row * 128 + lane * 2) = o;
}

// ---------------- f32 GEMM: Y (+)= X @ W^T (+ bias), optional relu ----------------
// X [M][128], W [128][128] row-major, Y [M][128]
// flags: bit0 accumulate, bit1 relu
#define BM 64
#define BK 32
__global__ __launch_bounds__(256) void gemm128(const float* __restrict__ X,
                                               const float* __restrict__ W,
                                               const float* __restrict__ bias,
                                               float* __restrict__ Y, int M, int flags) {
    __shared__ float Xs[BM][BK + 1];    // 64x33
    __shared__ float Ws[BK][128 + 4];   // 32x132 (transposed: Ws[k][n])
    int tid = threadIdx.x;
    int m0 = blockIdx.x * BM;
    int tm = tid >> 4;   // 0..15 -> rows tm*4..+3
    int tn = tid & 15;   // 0..15 -> cols tn*8..+7
    float acc[4][8] = {};
    for (int kt = 0; kt < 128; kt += BK) {
        {
            int r = tid >> 3;
            int kc = (tid & 7) * 4;
#pragma unroll
            for (int p = 0; p < 2; ++p) {
                int row = r + p * 32;
                int gm = m0 + row;
                float4 v = {0.f, 0.f, 0.f, 0.f};
                if (gm < M) v = *(const float4*)(X + (size_t)gm * 128 + kt + kc);
                Xs[row][kc + 0] = v.x;
                Xs[row][kc + 1] = v.y;
                Xs[row][kc + 2] = v.z;
                Xs[row][kc + 3] = v.w;
            }
        }
        {
#pragma unroll
            for (int c = 0; c < 4; ++c) {
                int idx = tid + c * 256;
                int n = idx >> 3;
                int kc = (idx & 7) * 4;
                float4 v = *(const float4*)(W + n * 128 + kt + kc);
                Ws[kc + 0][n] = v.x;
                Ws[kc + 1][n] = v.y;
                Ws[kc + 2][n] = v.z;
                Ws[kc + 3][n] = v.w;
            }
        }
        __syncthreads();
#pragma unroll 8
        for (int k = 0; k < BK; ++k) {
            float xf[4], wf[8];
#pragma unroll
            for (int q = 0; q < 4; ++q) xf[q] = Xs[tm * 4 + q][k];
#pragma unroll
            for (int q = 0; q < 8; ++q) wf[q] = Ws[k][tn * 8 + q];
#pragma unroll
            for (int a = 0; a < 4; ++a)
#pragma unroll
                for (int b = 0; b < 8; ++b) acc[a][b] += xf[a] * wf[b];
        }
        __syncthreads();
    }
    bool accum = flags & 1, relu = flags & 2;
#pragma unroll
    for (int a = 0; a < 4; ++a) {
        int gm = m0 + tm * 4 + a;
        if (gm >= M) continue;
        float* yrow = Y + (size_t)gm * 128 + tn * 8;
#pragma unroll
        for (int b = 0; b < 8; ++b) {
            float v = acc[a][b];
            if (bias) v += bias[tn * 8 + b];
            if (accum) v += yrow[b];
            if (relu) v = fmaxf(v, 0.f);
            yrow[b] = v;
        }
    }
}

// ---------------- host orchestration ----------------
extern "C" void kernel_launch(void* const* d_in, const int* in_sizes, int n_in,
                              void* d_out, int out_size, void* d_ws, size_t ws_size,
                              hipStream_t stream) {
    const float* emb[4] = {(const float*)d_in[0], (const float*)d_in[1],
                           (const float*)d_in[2], (const float*)d_in[3]};
    const float* W1_l = (const float*)d_in[4];
    const float* b1 = (const float*)d_in[5];
    const float* W1_r = (const float*)d_in[6];
    const float* W2_l = (const float*)d_in[7];
    const float* b2 = (const float*)d_in[8];
    const float* W2_r = (const float*)d_in[9];
    const float* ew[8];
    for (int i = 0; i < 8; ++i) ew[i] = (const float*)d_in[10 + i];
    const int* ei_buys = (const int*)d_in[18];
    const int* ei_sea = (const int*)d_in[19];
    const int* ei_mat = (const int*)d_in[20];
    const int* ei_in = (const int*)d_in[21];

    const int NT[4] = {NUSER, NPROD, NCAT, NQRY};
    const int rowOff[4] = {0, NUSER, NUSER + NPROD, NUSER + NPROD + NCAT};

    struct RelT { int s, d, E; const int* src; const int* dst; const float* w; };
    RelT rel[8] = {
        {0, 1, EBUYS, ei_buys, ei_buys + EBUYS, ew[0]},
        {1, 0, EBUYS, ei_buys + EBUYS, ei_buys, ew[1]},
        {0, 3, ESEARCH, ei_sea, ei_sea + ESEARCH, ew[2]},
        {3, 0, ESEARCH, ei_sea + ESEARCH, ei_sea, ew[3]},
        {3, 1, EMATCH, ei_mat, ei_mat + EMATCH, ew[4]},
        {1, 3, EMATCH, ei_mat + EMATCH, ei_mat, ew[5]},
        {1, 2, EIN, ei_in, ei_in + EIN, ew[6]},
        {2, 1, EIN, ei_in + EIN, ei_in, ew[7]},
    };
    const int lastRel[4] = {3, 7, 6, 5};  // last relation (in t-order) per dst type

    // ---- workspace carve ----
    char* p = (char*)d_ws;
    auto carve = [&](size_t bytes) {
        char* r = p;
        p += (bytes + 255) & ~(size_t)255;
        return r;
    };
    // offs arrays (n_dst+1 ints each)
    int* offs[8];
    for (int t = 0; t < 8; ++t) offs[t] = (int*)carve(((size_t)NT[rel[t].d] + 1) * 4);
    // fill/count arrays, contiguous for one memset
    size_t fillTot = 0;
    for (int t = 0; t < 8; ++t) fillTot += (size_t)NT[rel[t].d];
    int* fillBase = (int*)carve(fillTot * 4);
    int* fill[8];
    {
        size_t o = 0;
        for (int t = 0; t < 8; ++t) { fill[t] = fillBase + o; o += NT[rel[t].d]; }
    }
    // csr payload
    size_t Etot = 0;
    int eoff[8];
    for (int t = 0; t < 8; ++t) { eoff[t] = (int)Etot; Etot += rel[t].E; }
    int* csr_src = (int*)carve(Etot * 4);
    float* csr_w = (float*)carve(Etot * 4);
    int* bsums = (int*)carve(64 * 4);
    float* Wlsum = (float*)carve((size_t)8 * 16384 * 4);
    float* bsum = (float*)carve((size_t)8 * 128 * 4);
    float* aggbuf = (float*)carve((size_t)NUSER * 128 * 4);
    float* h = (float*)carve((size_t)(NUSER + NPROD + NCAT + NQRY) * 128 * 4);

    // ---- CSR build (once per call, reused by both layers) ----
    hipMemsetAsync(fillBase, 0, fillTot * 4, stream);
    for (int t = 0; t < 8; ++t)
        count_kernel<<<(rel[t].E + 255) / 256, 256, 0, stream>>>(rel[t].dst, rel[t].E, fill[t]);
    for (int t = 0; t < 8; ++t) {
        int n = NT[rel[t].d];
        int nb = (n + 4095) / 4096;
        scan_partial<<<nb, 256, 0, stream>>>(fill[t], n, bsums);
        scan_bsums<<<1, 64, 0, stream>>>(bsums, nb);
        scan_final<<<nb, 256, 0, stream>>>(fill[t], n, bsums, offs[t]);
    }
    hipMemsetAsync(fillBase, 0, fillTot * 4, stream);
    for (int t = 0; t < 8; ++t)
        fill_kernel<<<(rel[t].E + 255) / 256, 256, 0, stream>>>(
            rel[t].src, rel[t].dst, rel[t].w, rel[t].E, offs[t], fill[t],
            csr_src + eoff[t], csr_w + eoff[t]);

    // ---- pre-summed Wl / bias ----
    wlsum_kernel<<<8, 256, 0, stream>>>(W1_l, b1, W2_l, b2, Wlsum, bsum);

    // ---- two layers ----
    for (int layer = 0; layer < 2; ++layer) {
        const float* xin[4];
        float* yout[4];
        for (int d = 0; d < 4; ++d) {
            xin[d] = layer == 0 ? emb[d] : h + (size_t)rowOff[d] * 128;
            yout[d] = layer == 0 ? h + (size_t)rowOff[d] * 128
                                 : (float*)d_out + (size_t)rowOff[d] * 128;
        }
        const float* Wr = layer == 0 ? W1_r : W2_r;
        // self transform + bias (overwrite)
        for (int d = 0; d < 4; ++d)
            gemm128<<<(NT[d] + BM - 1) / BM, 256, 0, stream>>>(
                xin[d], Wlsum + (size_t)(layer * 4 + d) * 16384,
                bsum + (size_t)(layer * 4 + d) * 128, yout[d], NT[d], 0);
        // relation aggregates (accumulate; relu fused into last pass, layer 0 only)
        for (int t = 0; t < 8; ++t) {
            int dT = rel[t].d, n = NT[dT];
            agg_kernel<<<(n + 3) / 4, 256, 0, stream>>>(xin[rel[t].s], offs[t],
                                                        csr_src + eoff[t], csr_w + eoff[t],
                                                        aggbuf, n);
            int flags = 1 | ((layer == 0 && lastRel[dT] == t) ? 2 : 0);
            gemm128<<<(n + BM - 1) / BM, 256, 0, stream>>>(aggbuf, Wr + (size_t)t * 16384,
                                                           nullptr, yout[dT], n, flags);
        }
    }
}

// Round 2
// 2648.938 us; speedup vs baseline: 1.3292x; 1.3292x over previous
//
#include <hip/hip_runtime.h>

// ---------------- problem constants ----------------
#define NUSER 200000
#define NPROD 100000
#define NCAT    2000
#define NQRY   50000
#define EBUYS  500000
#define ESEARCH 300000
#define EMATCH  300000
#define EIN     100000

// type ids: 0=user 1=product 2=category 3=query
// relations t=0..7 (weight-stack index):
//  t0 user->product, t1 product->user, t2 user->query, t3 query->user,
//  t4 query->product, t5 product->query, t6 product->category, t7 category->product
// per-dst relation slots (must match wt_build's relsD):
//  user: {t1,t3}  product: {t0,t4,t7}  category: {t6}  query: {t2,t5}

// ---------------- CSR build ----------------
__global__ __launch_bounds__(256) void count_kernel(const int* __restrict__ dst, int E,
                                                    int* __restrict__ cnt) {
    int i = blockIdx.x * 256 + threadIdx.x;
    if (i < E) atomicAdd(&cnt[dst[i]], 1);
}

__global__ __launch_bounds__(256) void scan_partial(const int* __restrict__ cnt, int n,
                                                    int* __restrict__ bsums) {
    __shared__ int sd[256];
    int base = blockIdx.x * 4096;
    int s = 0;
    for (int j = threadIdx.x; j < 4096; j += 256) {
        int idx = base + j;
        s += (idx < n) ? cnt[idx] : 0;
    }
    sd[threadIdx.x] = s;
    __syncthreads();
    for (int st = 128; st > 0; st >>= 1) {
        if (threadIdx.x < st) sd[threadIdx.x] += sd[threadIdx.x + st];
        __syncthreads();
    }
    if (threadIdx.x == 0) bsums[blockIdx.x] = sd[0];
}

__global__ __launch_bounds__(64) void scan_bsums(int* __restrict__ bs, int nb) {
    int lane = threadIdx.x;
    int orig = (lane < nb) ? bs[lane] : 0;
    int v = orig;
    for (int off = 1; off < 64; off <<= 1) {
        int t = __shfl_up(v, off);
        if (lane >= off) v += t;
    }
    if (lane < nb) bs[lane] = v - orig;  // exclusive
}

__global__ __launch_bounds__(256) void scan_final(const int* __restrict__ cnt, int n,
                                                  const int* __restrict__ bsums,
                                                  int* __restrict__ offs) {
    __shared__ int tsum[256];
    int base = blockIdx.x * 4096;
    int tid = threadIdx.x;
    int local[16];
    int s = 0;
#pragma unroll
    for (int j = 0; j < 16; ++j) {
        int idx = base + tid * 16 + j;
        int v = (idx < n) ? cnt[idx] : 0;
        s += v;
        local[j] = s;
    }
    tsum[tid] = s;
    __syncthreads();
    int v = s;
    for (int off = 1; off < 256; off <<= 1) {
        int t = (tid >= off) ? tsum[tid - off] : 0;
        __syncthreads();
        v += t;
        tsum[tid] = v;
        __syncthreads();
    }
    int tpre = v - s;
    int bpre = bsums[blockIdx.x];
#pragma unroll
    for (int j = 0; j < 16; ++j) {
        int idx = base + tid * 16 + j;
        if (idx < n) offs[idx + 1] = bpre + tpre + local[j];
    }
    if (blockIdx.x == 0 && tid == 0) offs[0] = 0;
}

__global__ __launch_bounds__(256) void fill_kernel(const int* __restrict__ src,
                                                   const int* __restrict__ dst,
                                                   const float* __restrict__ w, int E,
                                                   const int* __restrict__ offs,
                                                   int* __restrict__ fill,
                                                   int* __restrict__ csr_src,
                                                   float* __restrict__ csr_w) {
    int i = blockIdx.x * 256 + threadIdx.x;
    if (i >= E) return;
    int d = dst[i];
    int slot = offs[d] + atomicAdd(&fill[d], 1);
    csr_src[slot] = src[i];
    csr_w[slot] = w[i];
}

// ---------------- fused weight build: WT[(1+k_d)*128][128], k-major ----------------
// WT block 0 = (sum_t Wl[t]) transposed; block 1+j = Wr[rels[j]] transposed.
// Also writes bsum[(l*4+d)*128].
__global__ __launch_bounds__(256) void wt_build(const float* __restrict__ W1_l,
                                                const float* __restrict__ b1,
                                                const float* __restrict__ W1_r,
                                                const float* __restrict__ W2_l,
                                                const float* __restrict__ b2,
                                                const float* __restrict__ W2_r,
                                                float* __restrict__ WT,
                                                float* __restrict__ bsum) {
    const int relsD[4][3] = {{1, 3, -1}, {0, 4, 7}, {6, -1, -1}, {2, 5, -1}};
    const int nrelD[4] = {2, 3, 1, 2};
    const int pre[4] = {0, 49152, 114688, 147456};  // floats, per-layer prefix
    int bid = blockIdx.x;
    int l = bid / 12, r = bid % 12;
    int d, s;
    if (r < 3) { d = 0; s = r; }
    else if (r < 7) { d = 1; s = r - 3; }
    else if (r < 9) { d = 2; s = r - 7; }
    else { d = 3; s = r - 9; }
    const float* Wl = l ? W2_l : W1_l;
    const float* Wr = l ? W2_r : W1_r;
    const float* bb = l ? b2 : b1;
    float* out = WT + (size_t)l * 196608 + pre[d] + (size_t)s * 16384;
    if (s == 0 && threadIdx.x < 128) {
        float acc = 0.f;
        for (int j = 0; j < nrelD[d]; ++j) acc += bb[relsD[d][j] * 128 + threadIdx.x];
        bsum[(l * 4 + d) * 128 + threadIdx.x] = acc;
    }
    __shared__ float tile[32][33];
    int rr = threadIdx.x >> 3;       // 0..31
    int cc = (threadIdx.x & 7) * 4;  // 0..28
    for (int ti = 0; ti < 4; ++ti)
        for (int tj = 0; tj < 4; ++tj) {
            float4 v = {0.f, 0.f, 0.f, 0.f};
            if (s == 0) {
                for (int j = 0; j < nrelD[d]; ++j) {
                    const float4 t4 = *(const float4*)(Wl + relsD[d][j] * 16384 +
                                                       (ti * 32 + rr) * 128 + tj * 32 + cc);
                    v.x += t4.x; v.y += t4.y; v.z += t4.z; v.w += t4.w;
                }
            } else {
                v = *(const float4*)(Wr + relsD[d][s - 1] * 16384 +
                                     (ti * 32 + rr) * 128 + tj * 32 + cc);
            }
            __syncthreads();  // protect previous iteration's reads
            tile[rr][cc + 0] = v.x;
            tile[rr][cc + 1] = v.y;
            tile[rr][cc + 2] = v.z;
            tile[rr][cc + 3] = v.w;
            __syncthreads();
            float4 w;
            w.x = tile[cc + 0][rr];
            w.y = tile[cc + 1][rr];
            w.z = tile[cc + 2][rr];
            w.w = tile[cc + 3][rr];
            *(float4*)(out + (size_t)(tj * 32 + rr) * 128 + ti * 32 + cc) = w;
        }
}

// ---------------- CSR gather-reduce (scatter-mean) into concat-slot layout ----------
// 32 lanes per dst row (float4 each), 2 rows per wave, 8 rows per block.
__global__ __launch_bounds__(256) void agg_kernel(const float* __restrict__ X, int ldx,
                                                  const int* __restrict__ offs,
                                                  const int* __restrict__ csr_src,
                                                  const float* __restrict__ csr_w,
                                                  float* __restrict__ out, int ldo,
                                                  int n_dst) {
    int row = blockIdx.x * 8 + (threadIdx.x >> 5);
    if (row >= n_dst) return;
    int lane = threadIdx.x & 31;
    int b = offs[row], e = offs[row + 1];
    float4 a = {0.f, 0.f, 0.f, 0.f};
    for (int i = b; i < e; ++i) {
        int s = csr_src[i];
        float w = csr_w[i];
        const float4 v = *(const float4*)(X + (size_t)s * ldx + lane * 4);
        a.x += w * v.x;
        a.y += w * v.y;
        a.z += w * v.z;
        a.w += w * v.w;
    }
    float inv = (e > b) ? 1.f / (float)(e - b) : 0.f;
    a.x *= inv; a.y *= inv; a.z *= inv; a.w *= inv;
    *(float4*)(out + (size_t)row * ldo + lane * 4) = a;
}

// ---------------- fused concat-K GEMM: Y = relu?([self|agg] @ WT + bias) -----------
// self [M][128] (stride lds_), agg [M][K-128] (stride lda_), WT [K][128] k-major,
// Y [M][128] (stride ldy). 128x128 tile, 256 threads, 8x8 per thread (lo/hi split).
#define GBM 128
#define GBK 16
__global__ __launch_bounds__(256) void gemm_fused(const float* __restrict__ Xself, int lds_,
                                                  const float* __restrict__ Xagg, int lda_,
                                                  const float* __restrict__ WT,
                                                  const float* __restrict__ bias,
                                                  float* __restrict__ Y, int ldy,
                                                  int M, int K, int relu) {
    __shared__ float Xs[GBK][GBM + 4];   // k-major
    __shared__ float Ws[GBK][128 + 4];   // k-major
    int tid = threadIdx.x;
    int m0 = blockIdx.x * GBM;
    int tm = tid >> 4;   // 0..15 -> rows {tm*4+a, 64+tm*4+a}
    int tn = tid & 15;   // 0..15 -> cols {tn*4+b, 64+tn*4+b}
    float acc[2][2][4][4] = {};  // [rh][ch][a][b]
    for (int kt = 0; kt < K; kt += GBK) {
        const float* Xsrc;
        int ldx, kc0;
        if (kt < 128) { Xsrc = Xself; ldx = lds_; kc0 = kt; }
        else { Xsrc = Xagg; ldx = lda_; kc0 = kt - 128; }
        // stage X (transpose to k-major): 128 rows x 16 k
#pragma unroll
        for (int p = 0; p < 2; ++p) {
            int idx = tid + p * 256;
            int m = idx >> 2, kc = (idx & 3) * 4;
            int gm = m0 + m;
            float4 v = {0.f, 0.f, 0.f, 0.f};
            if (gm < M) v = *(const float4*)(Xsrc + (size_t)gm * ldx + kc0 + kc);
            Xs[kc + 0][m] = v.x;
            Xs[kc + 1][m] = v.y;
            Xs[kc + 2][m] = v.z;
            Xs[kc + 3][m] = v.w;
        }
        // stage W (already k-major): rows kt..kt+15
#pragma unroll
        for (int p = 0; p < 2; ++p) {
            int idx = tid + p * 256;
            int kk = idx >> 5, col = (idx & 31) * 4;
            *(float4*)&Ws[kk][col] = *(const float4*)(WT + (size_t)(kt + kk) * 128 + col);
        }
        __syncthreads();
#pragma unroll
        for (int kk = 0; kk < GBK; ++kk) {
            float4 x0 = *(const float4*)&Xs[kk][tm * 4];
            float4 x1 = *(const float4*)&Xs[kk][64 + tm * 4];
            float4 w0 = *(const float4*)&Ws[kk][tn * 4];
            float4 w1 = *(const float4*)&Ws[kk][64 + tn * 4];
            float xa[2][4] = {{x0.x, x0.y, x0.z, x0.w}, {x1.x, x1.y, x1.z, x1.w}};
            float wb[2][4] = {{w0.x, w0.y, w0.z, w0.w}, {w1.x, w1.y, w1.z, w1.w}};
#pragma unroll
            for (int rh = 0; rh < 2; ++rh)
#pragma unroll
                for (int ch = 0; ch < 2; ++ch)
#pragma unroll
                    for (int a = 0; a < 4; ++a)
#pragma unroll
                        for (int b = 0; b < 4; ++b)
                            acc[rh][ch][a][b] += xa[rh][a] * wb[ch][b];
        }
        __syncthreads();
    }
#pragma unroll
    for (int rh = 0; rh < 2; ++rh)
#pragma unroll
        for (int a = 0; a < 4; ++a) {
            int gm = m0 + rh * 64 + tm * 4 + a;
            if (gm >= M) continue;
            float* yr = Y + (size_t)gm * ldy;
#pragma unroll
            for (int ch = 0; ch < 2; ++ch) {
                float4 v;
                v.x = acc[rh][ch][a][0] + bias[ch * 64 + tn * 4 + 0];
                v.y = acc[rh][ch][a][1] + bias[ch * 64 + tn * 4 + 1];
                v.z = acc[rh][ch][a][2] + bias[ch * 64 + tn * 4 + 2];
                v.w = acc[rh][ch][a][3] + bias[ch * 64 + tn * 4 + 3];
                if (relu) {
                    v.x = fmaxf(v.x, 0.f);
                    v.y = fmaxf(v.y, 0.f);
                    v.z = fmaxf(v.z, 0.f);
                    v.w = fmaxf(v.w, 0.f);
                }
                *(float4*)(yr + ch * 64 + tn * 4) = v;
            }
        }
}

// ---------------- host orchestration ----------------
extern "C" void kernel_launch(void* const* d_in, const int* in_sizes, int n_in,
                              void* d_out, int out_size, void* d_ws, size_t ws_size,
                              hipStream_t stream) {
    const float* emb[4] = {(const float*)d_in[0], (const float*)d_in[1],
                           (const float*)d_in[2], (const float*)d_in[3]};
    const float* W1_l = (const float*)d_in[4];
    const float* b1 = (const float*)d_in[5];
    const float* W1_r = (const float*)d_in[6];
    const float* W2_l = (const float*)d_in[7];
    const float* b2 = (const float*)d_in[8];
    const float* W2_r = (const float*)d_in[9];
    const float* ew[8];
    for (int i = 0; i < 8; ++i) ew[i] = (const float*)d_in[10 + i];
    const int* ei_buys = (const int*)d_in[18];
    const int* ei_sea = (const int*)d_in[19];
    const int* ei_mat = (const int*)d_in[20];
    const int* ei_in = (const int*)d_in[21];

    const int NT[4] = {NUSER, NPROD, NCAT, NQRY};
    const int rowOff[4] = {0, NUSER, NUSER + NPROD, NUSER + NPROD + NCAT};
    const int nrelD[4] = {2, 3, 1, 2};
    const int wtPre[4] = {0, 49152, 114688, 147456};

    struct RelT { int s, d, slot, E; const int* src; const int* dst; const float* w; };
    // slot assignment must match wt_build relsD: user{1,3} product{0,4,7} cat{6} query{2,5}
    RelT rel[8] = {
        {0, 1, 0, EBUYS,   ei_buys,          ei_buys + EBUYS,  ew[0]},  // t0
        {1, 0, 0, EBUYS,   ei_buys + EBUYS,  ei_buys,          ew[1]},  // t1
        {0, 3, 0, ESEARCH, ei_sea,           ei_sea + ESEARCH, ew[2]},  // t2
        {3, 0, 1, ESEARCH, ei_sea + ESEARCH, ei_sea,           ew[3]},  // t3
        {3, 1, 1, EMATCH,  ei_mat,           ei_mat + EMATCH,  ew[4]},  // t4
        {1, 3, 1, EMATCH,  ei_mat + EMATCH,  ei_mat,           ew[5]},  // t5
        {1, 2, 0, EIN,     ei_in,            ei_in + EIN,      ew[6]},  // t6
        {2, 1, 2, EIN,     ei_in + EIN,      ei_in,            ew[7]},  // t7
    };

    // ---- workspace carve ----
    char* p = (char*)d_ws;
    auto carve = [&](size_t bytes) {
        char* r = p;
        p += (bytes + 255) & ~(size_t)255;
        return r;
    };
    int* offs[8];
    for (int t = 0; t < 8; ++t) offs[t] = (int*)carve(((size_t)NT[rel[t].d] + 1) * 4);
    size_t fillTot = 0;
    for (int t = 0; t < 8; ++t) fillTot += (size_t)NT[rel[t].d];
    int* fillBase = (int*)carve(fillTot * 4);
    int* fill[8];
    {
        size_t o = 0;
        for (int t = 0; t < 8; ++t) { fill[t] = fillBase + o; o += NT[rel[t].d]; }
    }
    size_t Etot = 0;
    int eoff[8];
    for (int t = 0; t < 8; ++t) { eoff[t] = (int)Etot; Etot += rel[t].E; }
    int* csr_src = (int*)carve(Etot * 4);
    float* csr_w = (float*)carve(Etot * 4);
    int* bsums = (int*)carve(64 * 4);
    float* WT = (float*)carve((size_t)2 * 196608 * 4);
    float* bsum = (float*)carve((size_t)8 * 128 * 4);
    // concat aggregate buffer: per dst type, [n_d][128*k_d], all types resident
    size_t aoff[4];
    size_t atot = 0;
    for (int d = 0; d < 4; ++d) {
        aoff[d] = atot;
        atot += (size_t)NT[d] * 128 * nrelD[d];
    }
    float* aggbuf = (float*)carve(atot * 4);  // ~410.6 MB

    // ---- CSR build (once, reused by both layers) ----
    hipMemsetAsync(fillBase, 0, fillTot * 4, stream);
    for (int t = 0; t < 8; ++t)
        count_kernel<<<(rel[t].E + 255) / 256, 256, 0, stream>>>(rel[t].dst, rel[t].E, fill[t]);
    for (int t = 0; t < 8; ++t) {
        int n = NT[rel[t].d];
        int nb = (n + 4095) / 4096;
        scan_partial<<<nb, 256, 0, stream>>>(fill[t], n, bsums);
        scan_bsums<<<1, 64, 0, stream>>>(bsums, nb);
        scan_final<<<nb, 256, 0, stream>>>(fill[t], n, bsums, offs[t]);
    }
    hipMemsetAsync(fillBase, 0, fillTot * 4, stream);
    for (int t = 0; t < 8; ++t)
        fill_kernel<<<(rel[t].E + 255) / 256, 256, 0, stream>>>(
            rel[t].src, rel[t].dst, rel[t].w, rel[t].E, offs[t], fill[t],
            csr_src + eoff[t], csr_w + eoff[t]);

    // ---- fused transposed weights + summed bias ----
    wt_build<<<24, 256, 0, stream>>>(W1_l, b1, W1_r, W2_l, b2, W2_r, WT, bsum);

    float* dout = (float*)d_out;

    // ---- two layers; layer-0 output (h) lives in d_out, layer-1 GEMM is in-place ----
    for (int layer = 0; layer < 2; ++layer) {
        // all aggregations first (layer-1 must read h before GEMMs overwrite d_out)
        for (int t = 0; t < 8; ++t) {
            int sT = rel[t].s, dT = rel[t].d, n = NT[dT];
            const float* X = layer == 0 ? emb[sT] : dout + (size_t)rowOff[sT] * 128;
            agg_kernel<<<(n + 7) / 8, 256, 0, stream>>>(
                X, 128, offs[t], csr_src + eoff[t], csr_w + eoff[t],
                aggbuf + aoff[dT] + rel[t].slot * 128, 128 * nrelD[dT], n);
        }
        // one fused GEMM per dst type
        for (int d = 0; d < 4; ++d) {
            int n = NT[d];
            const float* self = layer == 0 ? emb[d] : dout + (size_t)rowOff[d] * 128;
            gemm_fused<<<(n + GBM - 1) / GBM, 256, 0, stream>>>(
                self, 128, aggbuf + aoff[d], 128 * nrelD[d],
                WT + (size_t)layer * 196608 + wtPre[d], bsum + (size_t)(layer * 4 + d) * 128,
                dout + (size_t)rowOff[d] * 128, 128, n, (1 + nrelD[d]) * 128,
                layer == 0 ? 1 : 0);
        }
    }
}